// Round 1
// baseline (1938.484 us; speedup 1.0000x reference)
//
#include <hip/hip_runtime.h>
#include <hip/hip_fp16.h>
#include <cstdint>

typedef _Float16 h2 __attribute__((ext_vector_type(2)));
typedef _Float16 h8 __attribute__((ext_vector_type(8)));
typedef float    f4 __attribute__((ext_vector_type(4)));
typedef uint32_t u4 __attribute__((ext_vector_type(4)));

// Shapes
#define BATCH 64
#define TSTEPS 1024
#define DDIM 512
#define HDIM 512

static __device__ __forceinline__ float fdot2(uint32_t w, uint32_t h, float acc) {
  return __builtin_amdgcn_fdot2(__builtin_bit_cast(h2, w), __builtin_bit_cast(h2, h), acc, false);
}

// ---------------------------------------------------------------------------
// prep: convert weights to f16, build pair-transposed Whh, bias sums.
//   wi16[dir][n][k]      f16   (2*512*512)
//   whT [dir][kpair][j]  u32   (f16x2: Whh[dir][j][2kp], Whh[dir][j][2kp+1])
//   bsum[dir][j]         f32
// ---------------------------------------------------------------------------
__global__ void prep_kernel(const float* __restrict__ Wih_f, const float* __restrict__ Whh_f,
                            const float* __restrict__ bih_f, const float* __restrict__ bhh_f,
                            const float* __restrict__ Wih_b, const float* __restrict__ Whh_b,
                            const float* __restrict__ bih_b, const float* __restrict__ bhh_b,
                            _Float16* __restrict__ wi16, uint32_t* __restrict__ whT,
                            float* __restrict__ bsum) {
  int i = blockIdx.x * 256 + threadIdx.x;
  if (i < 2 * 512 * 512) {
    const float* s = (i < 512 * 512) ? Wih_f : Wih_b;
    wi16[i] = (_Float16)s[i & (512 * 512 - 1)];
  }
  if (i < 2 * 256 * 512) {
    int d = i >> 17; int rem = i & ((1 << 17) - 1);
    int kp = rem >> 9; int j = rem & 511;
    const float* W = d ? Whh_b : Whh_f;
    h2 p; p[0] = (_Float16)W[j * 512 + 2 * kp]; p[1] = (_Float16)W[j * 512 + 2 * kp + 1];
    whT[i] = __builtin_bit_cast(uint32_t, p);
  }
  if (i < 2 * 512) {
    int d = i >> 9, j = i & 511;
    bsum[i] = d ? (bih_b[j] + bhh_b[j]) : (bih_f[j] + bhh_f[j]);
  }
}

// ---------------------------------------------------------------------------
// xp_gemm: xp[dir][m][n] = sum_d x[srow(m)][d]*Wih[dir][n][d] + bih[n]+bhh[n]
//   m = b*1024 + p (processing order); dir==1 reads x at time 1023-p.
//   128x128 tile, BK=32, 4 waves (2x2), mfma_f32_16x16x32_f16.
// ---------------------------------------------------------------------------
__global__ __launch_bounds__(256) void xp_gemm(const float* __restrict__ x,
                                               const _Float16* __restrict__ wi,
                                               const float* __restrict__ bsum,
                                               _Float16* __restrict__ xp) {
  __shared__ _Float16 As[128][40];   // stride 40 f16 = 80B (16B-aligned rows, odd dword stride)
  __shared__ _Float16 Bs[128][40];
  const int mt = blockIdx.x, nt = blockIdx.y, dir = blockIdx.z;
  const int m0 = mt * 128, n0 = nt * 128;
  const int tid = threadIdx.x;
  const int lane = tid & 63, w = tid >> 6;
  const int wr = w >> 1, wc = w & 1;
  const int ra = tid >> 1, hf = tid & 1;   // staging: 2 threads/row, 16 elems each

  const int mrow = m0 + ra;
  const int bb = mrow >> 10, pp = mrow & 1023;
  const int srow = dir ? ((bb << 10) + (1023 - pp)) : mrow;
  const float*    xbase = x + (size_t)srow * 512 + hf * 16;
  const _Float16* wbase = wi + (size_t)dir * 512 * 512 + (size_t)(n0 + ra) * 512 + hf * 16;

  f4 acc[4][4];
  #pragma unroll
  for (int a = 0; a < 4; ++a)
    #pragma unroll
    for (int b = 0; b < 4; ++b) acc[a][b] = (f4)0.f;

  for (int k0 = 0; k0 < 512; k0 += 32) {
    f4 x0 = *(const f4*)(xbase + k0);
    f4 x1 = *(const f4*)(xbase + k0 + 4);
    f4 x2 = *(const f4*)(xbase + k0 + 8);
    f4 x3 = *(const f4*)(xbase + k0 + 12);
    h8 b0 = *(const h8*)(wbase + k0);
    h8 b1 = *(const h8*)(wbase + k0 + 8);
    h8 a0, a1;
    #pragma unroll
    for (int u = 0; u < 4; ++u) {
      a0[u] = (_Float16)x0[u]; a0[4 + u] = (_Float16)x1[u];
      a1[u] = (_Float16)x2[u]; a1[4 + u] = (_Float16)x3[u];
    }
    __syncthreads();
    *(h8*)&As[ra][hf * 16]     = a0;
    *(h8*)&As[ra][hf * 16 + 8] = a1;
    *(h8*)&Bs[ra][hf * 16]     = b0;
    *(h8*)&Bs[ra][hf * 16 + 8] = b1;
    __syncthreads();
    h8 af[4], bf[4];
    #pragma unroll
    for (int fm = 0; fm < 4; ++fm)
      af[fm] = *(const h8*)&As[wr * 64 + fm * 16 + (lane & 15)][(lane >> 4) * 8];
    #pragma unroll
    for (int fn = 0; fn < 4; ++fn)
      bf[fn] = *(const h8*)&Bs[wc * 64 + fn * 16 + (lane & 15)][(lane >> 4) * 8];
    #pragma unroll
    for (int fm = 0; fm < 4; ++fm)
      #pragma unroll
      for (int fn = 0; fn < 4; ++fn)
        acc[fm][fn] = __builtin_amdgcn_mfma_f32_16x16x32_f16(af[fm], bf[fn], acc[fm][fn], 0, 0, 0);
  }

  float bsv[4];
  #pragma unroll
  for (int fn = 0; fn < 4; ++fn)
    bsv[fn] = bsum[dir * 512 + n0 + wc * 64 + fn * 16 + (lane & 15)];
  #pragma unroll
  for (int fm = 0; fm < 4; ++fm)
    #pragma unroll
    for (int fn = 0; fn < 4; ++fn)
      #pragma unroll
      for (int u = 0; u < 4; ++u) {
        int m = m0 + wr * 64 + fm * 16 + (lane >> 4) * 4 + u;
        int n = n0 + wc * 64 + fn * 16 + (lane & 15);
        xp[((size_t)dir << 25) + (size_t)m * 512 + n] = (_Float16)(acc[fm][fn][u] + bsv[fn]);
      }
}

// ---------------------------------------------------------------------------
// rnn_rec: one workgroup per (dir,b) chain. 1024 threads.
//   lane l: q = l>>8 (K-quarter, 64 h-pairs), r = l&255; outputs j0=r, j1=r+256.
//   Weights: w0[64] (j0, all pairs) + w1[32] (j1, pairs 0..31) in VGPRs;
//            pairs 32..63 of j1 in LDS (wl[32][1024]).
//   h kept as f16 pairs in LDS, read wave-uniform (broadcast).
// ---------------------------------------------------------------------------
__global__ __launch_bounds__(1024) void rnn_rec(const _Float16* __restrict__ xp,
                                                const uint32_t* __restrict__ whT,
                                                float* __restrict__ out) {
  extern __shared__ char smem[];
  uint32_t* wl   = (uint32_t*)smem;              // [32][1024] = 128 KB
  uint32_t* hl   = (uint32_t*)(smem + 131072);   // [256] f16x2 pairs = 1 KB
  float*    psum = (float*)(smem + 132096);      // [4][520] = 8320 B

  const int bid = blockIdx.x;
  const int dir = bid & 1, b = bid >> 1;
  const int l = threadIdx.x;
  const int q = l >> 8, r = l & 255;
  const uint32_t* wbase = whT + dir * (256 * 512);

  uint32_t w0[64], w1[32];
  #pragma unroll
  for (int p = 0; p < 64; ++p) w0[p] = wbase[(q * 64 + p) * 512 + r];
  #pragma unroll
  for (int p = 0; p < 32; ++p) w1[p] = wbase[(q * 64 + p) * 512 + 256 + r];
  #pragma unroll
  for (int p = 32; p < 64; ++p) wl[(p - 32) * 1024 + l] = wbase[(q * 64 + p) * 512 + 256 + r];
  if (l < 256) hl[l] = 0;
  __syncthreads();

  const _Float16* xpb = xp + ((size_t)(dir * 64 + b) << 19);
  float* op = out + ((size_t)(b * 2 + dir) << 19);

  for (int t = 0; t < TSTEPS; ++t) {
    float xpv = 0.f;
    if (l < 512) xpv = (float)xpb[t * 512 + l];   // prefetch; used after main loop
    float acc0 = 0.f, acc1 = 0.f;
    #pragma unroll
    for (int c = 0; c < 16; ++c) {
      u4 hq = *(const u4*)(hl + q * 64 + c * 4);  // wave-uniform broadcast read
      if (c < 8) {
        #pragma unroll
        for (int i2 = 0; i2 < 4; ++i2) {
          acc0 = fdot2(w0[c * 4 + i2], hq[i2], acc0);
          acc1 = fdot2(w1[c * 4 + i2], hq[i2], acc1);
        }
      } else {
        #pragma unroll
        for (int i2 = 0; i2 < 4; ++i2) {
          uint32_t wv = wl[((c - 8) * 4 + i2) * 1024 + l];   // conflict-free (lane-consecutive)
          acc0 = fdot2(w0[c * 4 + i2], hq[i2], acc0);
          acc1 = fdot2(wv, hq[i2], acc1);
        }
      }
    }
    psum[q * 520 + r]       = acc0;   // j = r
    psum[q * 520 + 256 + r] = acc1;   // j = r + 256
    __syncthreads();
    if (l < 512) {
      float s = psum[l] + psum[520 + l] + psum[1040 + l] + psum[1560 + l] + xpv;
      float e = __expf(2.f * s);
      float hv = 1.f - 2.f * __builtin_amdgcn_rcpf(e + 1.f);  // tanh(s); saturates correctly at +-inf
      op[t * 512 + l] = hv;
      ((_Float16*)hl)[l] = (_Float16)hv;
    }
    __syncthreads();
  }
}

// ---------------------------------------------------------------------------
extern "C" void kernel_launch(void* const* d_in, const int* in_sizes, int n_in,
                              void* d_out, int out_size, void* d_ws, size_t ws_size,
                              hipStream_t stream) {
  const float* x     = (const float*)d_in[0];
  const float* Wih_f = (const float*)d_in[1];
  const float* Whh_f = (const float*)d_in[2];
  const float* bih_f = (const float*)d_in[3];
  const float* bhh_f = (const float*)d_in[4];
  const float* Wih_b = (const float*)d_in[5];
  const float* Whh_b = (const float*)d_in[6];
  const float* bih_b = (const float*)d_in[7];
  const float* bhh_b = (const float*)d_in[8];

  char* ws = (char*)d_ws;
  _Float16* xp16 = (_Float16*)ws;                 // 2*64*1024*512 f16 = 128 MB
  _Float16* wi16 = (_Float16*)(ws + 134217728);   // 1 MB
  uint32_t* whT  = (uint32_t*)(ws + 135266304);   // 1 MB
  float*    bsum = (float*)(ws + 136314880);      // 4 KB
  float* out = (float*)d_out;

  prep_kernel<<<2048, 256, 0, stream>>>(Wih_f, Whh_f, bih_f, bhh_f,
                                        Wih_b, Whh_b, bih_b, bhh_b, wi16, whT, bsum);
  dim3 g(512, 4, 2);
  xp_gemm<<<g, 256, 0, stream>>>(x, wi16, bsum, xp16);

  const int REC_LDS = 140416;
  hipFuncSetAttribute((const void*)rnn_rec, hipFuncAttributeMaxDynamicSharedMemorySize, REC_LDS);
  rnn_rec<<<128, 1024, REC_LDS, stream>>>(xp16, whT, out);
}